// Round 5
// baseline (5077.337 us; speedup 1.0000x reference)
//
#include <hip/hip_runtime.h>
#include <stdint.h>

#define T_LEN 2048
#define L     1024
#define KBLK  16            // compute blocks (block KBLK is the gold block)
#define CPB   64            // columns per block; 4 per wave
#define TPB   1024
#define SPIN_MAX (1 << 18)

#define SCOPE_AGENT __HIP_MEMORY_SCOPE_AGENT

__device__ __forceinline__ uint64_t pack_su(int tag, float v) {
    return ((uint64_t)(uint32_t)tag << 32) | (uint64_t)__float_as_uint(v);
}

__global__ __launch_bounds__(TPB, 1)
void crf_forward(const float* __restrict__ feats,
                 const float* __restrict__ transfer,
                 const int* __restrict__ target,
                 float* __restrict__ out,
                 uint64_t* __restrict__ ws64)
{
    __shared__ __align__(16) float qbuf[2][L];      // 8 KB: exp(prev - sloc), double-buffered
    __shared__ float red[32];

    uint64_t* buf0 = ws64;                          // tagged score buffers (double-buffered)
    uint64_t* buf1 = ws64 + L;
    uint64_t* goldslot = ws64 + 2 * L;

    const int b   = blockIdx.x;
    const int tid = threadIdx.x;

    // ---------------- gold-score block (independent of the chain) ----------------
    if (b == KBLK) {
        float s = 0.f;
        for (int t = tid; t < T_LEN; t += TPB)
            s += feats[t * L + target[t]];
        for (int t = tid; t < T_LEN - 1; t += TPB)
            s += transfer[target[t] * L + target[t + 1]];
        #pragma unroll
        for (int m = 32; m; m >>= 1) s += __shfl_xor(s, m, 64);
        if ((tid & 63) == 0) red[tid >> 6] = s;
        __syncthreads();
        if (tid == 0) {
            float g = 0.f;
            #pragma unroll
            for (int k = 0; k < TPB / 64; ++k) g += red[k];
            __hip_atomic_store(goldslot, pack_su(1, g), __ATOMIC_RELAXED, SCOPE_AGENT);
        }
        return;
    }

    const int lane = tid & 63;
    const int wv   = tid >> 6;                      // wave 0..15
    const int gcb  = b * CPB + 4 * wv;              // this wave's first global column
    // lane -> column-within-wave mapping fixed by the split-reduction below:
    const int cl   = 2 * (lane & 1) + ((lane >> 1) & 1);   // 0..3, bijective on lanes 0..3
    const int shslot = b * CPB;                     // block-uniform exp-shift source column

    // ---------------- stage E = exp(transfer) into REGISTERS ----------------
    // lane handles rows i = lane + 64k (k=0..15), columns gcb..gcb+3. 64 fp32 VGPRs.
    float E[16][4];
    #pragma unroll
    for (int k = 0; k < 16; ++k) {
        const float4 r = *(const float4*)(transfer + (lane + 64 * k) * L + gcb);
        E[k][0] = __expf(r.x); E[k][1] = __expf(r.y);
        E[k][2] = __expf(r.z); E[k][3] = __expf(r.w);
    }

    // ---------------- init: step-0 scores = feats[0], tag 0 ----------------
    if (tid < CPB) {
        int j = b * CPB + tid;
        __hip_atomic_store(&buf0[j], pack_su(0, feats[j]), __ATOMIC_RELAXED, SCOPE_AGENT);
    }

    // ---------------- sequential chain: ONE barrier per step ----------------
    for (int t = 1; t < T_LEN; ++t) {
        uint64_t* rbuf = (t & 1) ? buf0 : buf1;     // holds step t-1
        uint64_t* wbuf = (t & 1) ? buf1 : buf0;     // will hold step t
        const int expect = t - 1;

        // emission for my column (global load overlaps the poll)
        const float fe = feats[t * L + gcb + cl];

        // thin poll: ONE own slot per thread (wave = 8 lines, 1 coalesced req)
        // + block-uniform broadcast slot (1 req/wave).
        uint64_t v, vs;
        int n = 0;
        for (;;) {
            v  = __hip_atomic_load(rbuf + tid,    __ATOMIC_RELAXED, SCOPE_AGENT);
            vs = __hip_atomic_load(rbuf + shslot, __ATOMIC_RELAXED, SCOPE_AGENT);
            bool ready = ((int)(v >> 32) >= expect) & ((int)(vs >> 32) >= expect);
            if (ready || ++n >= SPIN_MAX) break;
        }
        const float sloc = __uint_as_float((uint32_t)vs);

        // q = exp(prev - sloc) -> LDS broadcast (double-buffered)
        float* qb = qbuf[t & 1];
        qb[tid] = __expf(__uint_as_float((uint32_t)v) - sloc);
        __syncthreads();

        // matvec from registers: acc[c] += q[lane+64k] * E[k][c]
        float a0 = 0.f, a1 = 0.f, a2 = 0.f, a3 = 0.f;
        #pragma unroll
        for (int k = 0; k < 16; ++k) {
            const float q = qb[lane + 64 * k];       // conflict-free ds_read_b32
            a0 += q * E[k][0]; a1 += q * E[k][1];
            a2 += q * E[k][2]; a3 += q * E[k][3];
        }

        // split-reduction over 64 lanes: 4 accs -> 1 value per lane, col = cl
        {
            const bool hi1 = lane & 1;
            float s0 = hi1 ? a0 : a2;  float r0 = __shfl_xor(s0, 1, 64);
            float s1 = hi1 ? a1 : a3;  float r1 = __shfl_xor(s1, 1, 64);
            a0 = (hi1 ? a2 : a0) + r0;
            a1 = (hi1 ? a3 : a1) + r1;
            const bool hi2 = lane & 2;
            float s2 = hi2 ? a0 : a1;  float r2 = __shfl_xor(s2, 2, 64);
            a0 = (hi2 ? a1 : a0) + r2;
        }
        float s = a0;
        s += __shfl_xor(s, 4, 64);
        s += __shfl_xor(s, 8, 64);
        s += __shfl_xor(s, 16, 64);
        s += __shfl_xor(s, 32, 64);

        const float nv = sloc + __logf(s) + fe;     // new score for column gcb+cl
        if (lane < 4)
            __hip_atomic_store(&wbuf[gcb + cl], pack_su(t, nv), __ATOMIC_RELAXED, SCOPE_AGENT);
    }

    // ---------------- epilogue: block 0 computes logZ - gold ----------------
    if (b == 0) {
        uint64_t v;                                  // t=2047 (odd) wrote buf1
        int n = 0;
        for (;;) {
            v = __hip_atomic_load(buf1 + tid, __ATOMIC_RELAXED, SCOPE_AGENT);
            if ((int)(v >> 32) >= T_LEN - 1 || ++n >= SPIN_MAX) break;
        }
        const float val = __uint_as_float((uint32_t)v);
        float mx = val;
        #pragma unroll
        for (int m = 32; m; m >>= 1) mx = fmaxf(mx, __shfl_xor(mx, m, 64));
        if (lane == 0) red[wv] = mx;
        __syncthreads();
        float M = red[0];
        #pragma unroll
        for (int k = 1; k < 16; ++k) M = fmaxf(M, red[k]);
        float sm = __expf(val - M);
        #pragma unroll
        for (int m = 32; m; m >>= 1) sm += __shfl_xor(sm, m, 64);
        if (lane == 0) red[16 + wv] = sm;
        __syncthreads();
        if (tid == 0) {
            float S = 0.f;
            #pragma unroll
            for (int k = 0; k < 16; ++k) S += red[16 + k];
            const float lse = M + __logf(S);
            uint64_t g = __hip_atomic_load(goldslot, __ATOMIC_RELAXED, SCOPE_AGENT);
            int n2 = 0;
            while ((int)(g >> 32) < 1 && ++n2 < SPIN_MAX)
                g = __hip_atomic_load(goldslot, __ATOMIC_RELAXED, SCOPE_AGENT);
            out[0] = lse - __uint_as_float((uint32_t)g);
        }
    }
}

extern "C" void kernel_launch(void* const* d_in, const int* in_sizes, int n_in,
                              void* d_out, int out_size, void* d_ws, size_t ws_size,
                              hipStream_t stream) {
    const float* feats    = (const float*)d_in[0];
    const float* transfer = (const float*)d_in[1];
    const int*   target   = (const int*)d_in[2];
    float* out = (float*)d_out;
    uint64_t* ws64 = (uint64_t*)d_ws;   // needs (2*L + 1) * 8 = 16392 bytes

    hipLaunchKernelGGL(crf_forward, dim3(KBLK + 1), dim3(TPB), 0, stream,
                       feats, transfer, target, out, ws64);
}

// Round 8
// 4717.191 us; speedup vs baseline: 1.0763x; 1.0763x over previous
//
#include <hip/hip_runtime.h>
#include <stdint.h>

#define T_LEN 2048
#define L     1024
#define KBLK  64            // compute blocks (block KBLK is the gold block)
#define CPB   16            // columns per block; 4 per wave
#define TPB   256
#define SPIN_MAX (1 << 17)

#define SCOPE_AGENT __HIP_MEMORY_SCOPE_AGENT
#define LDA(p) __hip_atomic_load((p), __ATOMIC_RELAXED, SCOPE_AGENT)

__device__ __forceinline__ uint64_t pack_su(int tag, float v) {
    return ((uint64_t)(uint32_t)tag << 32) | (uint64_t)__float_as_uint(v);
}

__global__ __launch_bounds__(TPB, 1)
void crf_forward(const float* __restrict__ feats,
                 const float* __restrict__ transfer,
                 const int* __restrict__ target,
                 float* __restrict__ out,
                 uint64_t* __restrict__ ws64)
{
    __shared__ __align__(16) float qbuf[2][L];      // 8 KB: exp(prev - sloc), double-buffered
    __shared__ float red[8];

    uint64_t* buf0 = ws64;                          // tagged score buffers (double-buffered)
    uint64_t* buf1 = ws64 + L;
    uint64_t* goldslot = ws64 + 2 * L;

    const int b   = blockIdx.x;
    const int tid = threadIdx.x;

    // ---------------- gold-score block (independent of the chain) ----------------
    if (b == KBLK) {
        float s = 0.f;
        for (int t = tid; t < T_LEN; t += TPB)
            s += feats[t * L + target[t]];
        for (int t = tid; t < T_LEN - 1; t += TPB)
            s += transfer[target[t] * L + target[t + 1]];
        #pragma unroll
        for (int m = 32; m; m >>= 1) s += __shfl_xor(s, m, 64);
        if ((tid & 63) == 0) red[tid >> 6] = s;
        __syncthreads();
        if (tid == 0) {
            float g = red[0] + red[1] + red[2] + red[3];
            __hip_atomic_store(goldslot, pack_su(1, g), __ATOMIC_RELAXED, SCOPE_AGENT);
        }
        return;
    }

    const int lane = tid & 63;
    const int wv   = tid >> 6;                      // wave 0..3
    const int gcb  = b * CPB + 4 * wv;              // this wave's first global column
    // lane -> column-within-wave mapping fixed by the split-reduction below:
    const int cl   = 2 * (lane & 1) + ((lane >> 1) & 1);   // 0..3, bijective on lanes 0..3
    const int shslot = b * CPB;                     // block-uniform exp-shift source column

    // ---------------- stage E = exp(transfer) into REGISTERS ----------------
    // lane handles rows i = lane + 64k (k=0..15), columns gcb..gcb+3. 64 fp32 VGPRs.
    float E[16][4];
    #pragma unroll
    for (int k = 0; k < 16; ++k) {
        const float4 r = *(const float4*)(transfer + (lane + 64 * k) * L + gcb);
        E[k][0] = __expf(r.x); E[k][1] = __expf(r.y);
        E[k][2] = __expf(r.z); E[k][3] = __expf(r.w);
    }

    // ---------------- init: step-0 scores = feats[0], tag 0 ----------------
    if (tid < CPB) {
        int j = b * CPB + tid;
        __hip_atomic_store(&buf0[j], pack_su(0, feats[j]), __ATOMIC_RELAXED, SCOPE_AGENT);
    }

    // ---------------- sequential chain: ONE barrier per step ----------------
    for (int t = 1; t < T_LEN; ++t) {
        uint64_t* rbuf = (t & 1) ? buf0 : buf1;     // holds step t-1
        uint64_t* wbuf = (t & 1) ? buf1 : buf0;     // will hold step t
        const int expect = t - 1;

        // emission for my column (global load overlaps the poll)
        const float fe = feats[t * L + gcb + cl];

        // ---- software-pipelined tag-spin: 2 poll batches in flight ----
        // batch = my 4 contiguous slots + block-uniform shift slot (5 loads).
        // Issue batch B, THEN check batch A: the compiler's waitcnt pass waits
        // only on A's loads (partial vmcnt), so B overlaps A's check -> the
        // sampling quantum drops from ~L to ~L/2. Semantics identical to R4.
        const uint64_t* rp = rbuf + 4 * tid;
        uint64_t a0, a1, a2, a3, as;
        a0 = LDA(rp + 0); a1 = LDA(rp + 1);
        a2 = LDA(rp + 2); a3 = LDA(rp + 3);
        as = LDA(rbuf + shslot);
        {
            bool readyA = ((int)(a0 >> 32) >= expect) & ((int)(a1 >> 32) >= expect) &
                          ((int)(a2 >> 32) >= expect) & ((int)(a3 >> 32) >= expect) &
                          ((int)(as >> 32) >= expect);
            int n = 0;
            while (!readyA && ++n < SPIN_MAX) {
                // issue next batch before checking the previous one
                uint64_t b0 = LDA(rp + 0), b1 = LDA(rp + 1);
                uint64_t b2 = LDA(rp + 2), b3 = LDA(rp + 3);
                uint64_t bs = LDA(rbuf + shslot);
                readyA = ((int)(a0 >> 32) >= expect) & ((int)(a1 >> 32) >= expect) &
                         ((int)(a2 >> 32) >= expect) & ((int)(a3 >> 32) >= expect) &
                         ((int)(as >> 32) >= expect);
                // rotate: the just-issued batch becomes the one checked next
                a0 = b0; a1 = b1; a2 = b2; a3 = b3; as = bs;
                if (readyA) { a0 = b0; }            // values already rotated; recheck below
            }
            // after rotation the satisfying values may be in the rotated regs;
            // one final confirming pass (cheap: data is already resident/ready)
            int m = 0;
            for (;;) {
                bool ok = ((int)(a0 >> 32) >= expect) & ((int)(a1 >> 32) >= expect) &
                          ((int)(a2 >> 32) >= expect) & ((int)(a3 >> 32) >= expect) &
                          ((int)(as >> 32) >= expect);
                if (ok || ++m >= SPIN_MAX) break;
                a0 = LDA(rp + 0); a1 = LDA(rp + 1);
                a2 = LDA(rp + 2); a3 = LDA(rp + 3);
                as = LDA(rbuf + shslot);
            }
        }
        const float sloc = __uint_as_float((uint32_t)as);

        // q = exp(prev - sloc) -> LDS broadcast (double-buffered)
        float* qb = qbuf[t & 1];
        float4 qv;
        qv.x = __expf(__uint_as_float((uint32_t)a0) - sloc);
        qv.y = __expf(__uint_as_float((uint32_t)a1) - sloc);
        qv.z = __expf(__uint_as_float((uint32_t)a2) - sloc);
        qv.w = __expf(__uint_as_float((uint32_t)a3) - sloc);
        ((float4*)qb)[tid] = qv;
        __syncthreads();

        // matvec from registers: acc[c] += q[lane+64k] * E[k][c]
        float a0f = 0.f, a1f = 0.f, a2f = 0.f, a3f = 0.f;
        #pragma unroll
        for (int k = 0; k < 16; ++k) {
            const float q = qb[lane + 64 * k];       // conflict-free ds_read_b32
            a0f += q * E[k][0]; a1f += q * E[k][1];
            a2f += q * E[k][2]; a3f += q * E[k][3];
        }

        // split-reduction over 64 lanes: 4 accs -> 1 value per lane, col = cl
        {
            const bool hi1 = lane & 1;
            float s0 = hi1 ? a0f : a2f;  float r0 = __shfl_xor(s0, 1, 64);
            float s1 = hi1 ? a1f : a3f;  float r1 = __shfl_xor(s1, 1, 64);
            a0f = (hi1 ? a2f : a0f) + r0;
            a1f = (hi1 ? a3f : a1f) + r1;
            const bool hi2 = lane & 2;
            float s2 = hi2 ? a0f : a1f;  float r2 = __shfl_xor(s2, 2, 64);
            a0f = (hi2 ? a1f : a0f) + r2;
        }
        float s = a0f;
        s += __shfl_xor(s, 4, 64);
        s += __shfl_xor(s, 8, 64);
        s += __shfl_xor(s, 16, 64);
        s += __shfl_xor(s, 32, 64);

        const float nv = sloc + __logf(s) + fe;     // new score for column gcb+cl
        if (lane < 4)
            __hip_atomic_store(&wbuf[gcb + cl], pack_su(t, nv), __ATOMIC_RELAXED, SCOPE_AGENT);
    }

    // ---------------- epilogue: block 0 computes logZ - gold ----------------
    if (b == 0) {
        const uint64_t* fp = buf1 + 4 * tid;        // t=2047 (odd) wrote buf1
        uint64_t v0, v1, v2, v3;
        int n = 0;
        for (;;) {
            v0 = LDA(fp + 0); v1 = LDA(fp + 1);
            v2 = LDA(fp + 2); v3 = LDA(fp + 3);
            bool ready = ((int)(v0 >> 32) >= T_LEN - 1) & ((int)(v1 >> 32) >= T_LEN - 1) &
                         ((int)(v2 >> 32) >= T_LEN - 1) & ((int)(v3 >> 32) >= T_LEN - 1);
            if (ready || ++n >= SPIN_MAX) break;
        }
        float sv[4] = { __uint_as_float((uint32_t)v0), __uint_as_float((uint32_t)v1),
                        __uint_as_float((uint32_t)v2), __uint_as_float((uint32_t)v3) };
        float mx = fmaxf(fmaxf(sv[0], sv[1]), fmaxf(sv[2], sv[3]));
        #pragma unroll
        for (int m = 32; m; m >>= 1) mx = fmaxf(mx, __shfl_xor(mx, m, 64));
        if ((tid & 63) == 0) red[tid >> 6] = mx;
        __syncthreads();
        const float M = fmaxf(fmaxf(red[0], red[1]), fmaxf(red[2], red[3]));
        float sm = 0.f;
        #pragma unroll
        for (int k = 0; k < 4; ++k) sm += __expf(sv[k] - M);
        #pragma unroll
        for (int m = 32; m; m >>= 1) sm += __shfl_xor(sm, m, 64);
        if ((tid & 63) == 0) red[4 + (tid >> 6)] = sm;
        __syncthreads();
        if (tid == 0) {
            const float S = red[4] + red[5] + red[6] + red[7];
            const float lse = M + __logf(S);
            uint64_t g = LDA(goldslot);
            int n2 = 0;
            while ((int)(g >> 32) < 1 && ++n2 < SPIN_MAX)
                g = LDA(goldslot);
            out[0] = lse - __uint_as_float((uint32_t)g);
        }
    }
}

extern "C" void kernel_launch(void* const* d_in, const int* in_sizes, int n_in,
                              void* d_out, int out_size, void* d_ws, size_t ws_size,
                              hipStream_t stream) {
    const float* feats    = (const float*)d_in[0];
    const float* transfer = (const float*)d_in[1];
    const int*   target   = (const int*)d_in[2];
    float* out = (float*)d_out;
    uint64_t* ws64 = (uint64_t*)d_ws;   // needs (2*L + 1) * 8 = 16392 bytes

    hipLaunchKernelGGL(crf_forward, dim3(KBLK + 1), dim3(TPB), 0, stream,
                       feats, transfer, target, out, ws64);
}

// Round 10
// 2298.078 us; speedup vs baseline: 2.2094x; 2.0527x over previous
//
#include <hip/hip_runtime.h>
#include <stdint.h>

#define T_LEN 2048
#define L     1024
#define NFB   64            // forward blocks: 0..63
#define GOLDB 128           // gold block (meet-in-middle grid)
#define CPB   16            // columns (rows) per block; 4 per wave
#define TPB   256
#define TMID  1023          // forward computes f_{1023}; backward computes b_{1023}
#define BSTEPS 1024         // backward step count (s=1..1024, emission row t=2048-s)
#define SPIN_MAX (1 << 14)  // bounded: wedge exits in ~2s, normal use ~1-3 iters

#define SCOPE_AGENT __HIP_MEMORY_SCOPE_AGENT
#define LDA(p) __hip_atomic_load((p), __ATOMIC_RELAXED, SCOPE_AGENT)
#define STA(p, v) __hip_atomic_store((p), (v), __ATOMIC_RELAXED, SCOPE_AGENT)

__device__ __forceinline__ uint64_t pack_su(int tag, float v) {
    return ((uint64_t)(uint32_t)tag << 32) | (uint64_t)__float_as_uint(v);
}

// =====================================================================
// Meet-in-the-middle kernel: forward chain (blocks 0..63, 1023 steps) +
// backward chain (blocks 64..127, 1024 steps) + gold block (128).
// Requires ws >= (4*L + 1) * 8 = 32776 bytes.
// =====================================================================
__global__ __launch_bounds__(TPB, 1)
void crf_mitm(const float* __restrict__ feats,
              const float* __restrict__ transfer,
              const int* __restrict__ target,
              float* __restrict__ out,
              uint64_t* __restrict__ ws64)
{
    __shared__ __align__(16) float qbuf[2][L];      // 8 KB, double-buffered
    __shared__ float red[8];

    uint64_t* fb0 = ws64;                           // forward tagged buffers
    uint64_t* fb1 = ws64 + L;
    uint64_t* bb0 = ws64 + 2 * L;                   // backward tagged buffers
    uint64_t* bb1 = ws64 + 3 * L;
    uint64_t* goldslot = ws64 + 4 * L;

    const int b    = blockIdx.x;
    const int tid  = threadIdx.x;
    const int lane = tid & 63;
    const int wv   = tid >> 6;                      // wave 0..3
    // lane -> slot-within-wave mapping fixed by the split-reduction below:
    const int cl   = 2 * (lane & 1) + ((lane >> 1) & 1);   // bijective on lanes 0..3

    // ---------------- gold-score block ----------------
    if (b == GOLDB) {
        float s = 0.f;
        for (int t = tid; t < T_LEN; t += TPB)
            s += feats[t * L + target[t]];
        for (int t = tid; t < T_LEN - 1; t += TPB)
            s += transfer[target[t] * L + target[t + 1]];
        #pragma unroll
        for (int m = 32; m; m >>= 1) s += __shfl_xor(s, m, 64);
        if (lane == 0) red[wv] = s;
        __syncthreads();
        if (tid == 0) {
            float g = red[0] + red[1] + red[2] + red[3];
            STA(goldslot, pack_su(1, g));
        }
        return;
    }

    if (b < NFB) {
        // ================= FORWARD chain (R4 body, 1023 steps) =================
        const int gcb    = b * CPB + 4 * wv;        // wave's first global column
        const int shslot = b * CPB;                 // block-uniform exp-shift slot

        float E[16][4];                             // E[k][c]=exp(transfer[lane+64k][gcb+c])
        #pragma unroll
        for (int k = 0; k < 16; ++k) {
            const float4 r = *(const float4*)(transfer + (size_t)(lane + 64 * k) * L + gcb);
            E[k][0] = __expf(r.x); E[k][1] = __expf(r.y);
            E[k][2] = __expf(r.z); E[k][3] = __expf(r.w);
        }

        if (tid < CPB) {
            int j = b * CPB + tid;
            STA(&fb0[j], pack_su(0, feats[j]));
        }

        for (int t = 1; t <= TMID; ++t) {
            uint64_t* rbuf = (t & 1) ? fb0 : fb1;
            uint64_t* wbuf = (t & 1) ? fb1 : fb0;
            const int expect = t - 1;

            const float fe = feats[(size_t)t * L + gcb + cl];   // overlaps poll

            const uint64_t* rp = rbuf + 4 * tid;
            uint64_t v0, v1, v2, v3, vs;
            int n = 0;
            for (;;) {
                v0 = LDA(rp + 0); v1 = LDA(rp + 1);
                v2 = LDA(rp + 2); v3 = LDA(rp + 3);
                vs = LDA(rbuf + shslot);
                bool ready = ((int)(v0 >> 32) >= expect) & ((int)(v1 >> 32) >= expect) &
                             ((int)(v2 >> 32) >= expect) & ((int)(v3 >> 32) >= expect) &
                             ((int)(vs >> 32) >= expect);
                if (ready || ++n >= SPIN_MAX) break;
            }
            const float sloc = __uint_as_float((uint32_t)vs);

            float* qb = qbuf[t & 1];
            float4 qv;
            qv.x = __expf(__uint_as_float((uint32_t)v0) - sloc);
            qv.y = __expf(__uint_as_float((uint32_t)v1) - sloc);
            qv.z = __expf(__uint_as_float((uint32_t)v2) - sloc);
            qv.w = __expf(__uint_as_float((uint32_t)v3) - sloc);
            ((float4*)qb)[tid] = qv;
            __syncthreads();

            float a0 = 0.f, a1 = 0.f, a2 = 0.f, a3 = 0.f;
            #pragma unroll
            for (int k = 0; k < 16; ++k) {
                const float q = qb[lane + 64 * k];   // conflict-free ds_read_b32
                a0 += q * E[k][0]; a1 += q * E[k][1];
                a2 += q * E[k][2]; a3 += q * E[k][3];
            }

            {   // split-reduction: 4 accs -> 1 per lane (col = cl)
                const bool h1 = lane & 1;
                float s0 = h1 ? a0 : a2;  float r0 = __shfl_xor(s0, 1, 64);
                float s1 = h1 ? a1 : a3;  float r1 = __shfl_xor(s1, 1, 64);
                a0 = (h1 ? a2 : a0) + r0;
                a1 = (h1 ? a3 : a1) + r1;
                const bool h2 = lane & 2;
                float s2 = h2 ? a0 : a1;  float r2 = __shfl_xor(s2, 2, 64);
                a0 = (h2 ? a1 : a0) + r2;
            }
            float s = a0;
            s += __shfl_xor(s, 4, 64);
            s += __shfl_xor(s, 8, 64);
            s += __shfl_xor(s, 16, 64);
            s += __shfl_xor(s, 32, 64);

            const float nv = sloc + __logf(s) + fe;
            if (lane < 4)
                STA(&wbuf[gcb + cl], pack_su(t, nv));
        }

        // ---------- block 0: combine logZ = lse(f_{1023} + b_{1023}) - gold ----------
        if (b == 0) {
            const uint64_t* fp = fb1 + 4 * tid;     // t=1023 odd -> fb1
            const uint64_t* bp = bb0 + 4 * tid;     // s=1024 even -> bb0
            uint64_t f0, f1, f2, f3, g0, g1, g2, g3;
            int n = 0;
            for (;;) {
                f0 = LDA(fp + 0); f1 = LDA(fp + 1); f2 = LDA(fp + 2); f3 = LDA(fp + 3);
                g0 = LDA(bp + 0); g1 = LDA(bp + 1); g2 = LDA(bp + 2); g3 = LDA(bp + 3);
                bool ready = ((int)(f0 >> 32) >= TMID) & ((int)(f1 >> 32) >= TMID) &
                             ((int)(f2 >> 32) >= TMID) & ((int)(f3 >> 32) >= TMID) &
                             ((int)(g0 >> 32) >= BSTEPS) & ((int)(g1 >> 32) >= BSTEPS) &
                             ((int)(g2 >> 32) >= BSTEPS) & ((int)(g3 >> 32) >= BSTEPS);
                if (ready || ++n >= SPIN_MAX) break;
            }
            float sv[4] = {
                __uint_as_float((uint32_t)f0) + __uint_as_float((uint32_t)g0),
                __uint_as_float((uint32_t)f1) + __uint_as_float((uint32_t)g1),
                __uint_as_float((uint32_t)f2) + __uint_as_float((uint32_t)g2),
                __uint_as_float((uint32_t)f3) + __uint_as_float((uint32_t)g3) };
            float mx = fmaxf(fmaxf(sv[0], sv[1]), fmaxf(sv[2], sv[3]));
            #pragma unroll
            for (int m = 32; m; m >>= 1) mx = fmaxf(mx, __shfl_xor(mx, m, 64));
            if (lane == 0) red[wv] = mx;
            __syncthreads();
            const float M = fmaxf(fmaxf(red[0], red[1]), fmaxf(red[2], red[3]));
            float sm = 0.f;
            #pragma unroll
            for (int k = 0; k < 4; ++k) sm += __expf(sv[k] - M);
            #pragma unroll
            for (int m = 32; m; m >>= 1) sm += __shfl_xor(sm, m, 64);
            if (lane == 0) red[4 + wv] = sm;
            __syncthreads();
            if (tid == 0) {
                const float S = red[4] + red[5] + red[6] + red[7];
                const float lse = M + __logf(S);
                uint64_t g = LDA(goldslot);
                int n2 = 0;
                while ((int)(g >> 32) < 1 && ++n2 < SPIN_MAX) g = LDA(goldslot);
                out[0] = lse - __uint_as_float((uint32_t)g);
            }
        }
        return;
    }

    // ================= BACKWARD chain (blocks 64..127, 1024 steps) =================
    {
        const int rb      = b - NFB;                // 0..63
        const int rowbase = rb * CPB + 4 * wv;      // wave's first global row
        const int shslot  = rb * CPB;               // block-uniform shift slot

        // E[k][r] = exp(transfer[(rowbase+r)*L + lane+64k]) — coalesced staging
        float E[16][4];
        #pragma unroll
        for (int r = 0; r < 4; ++r) {
            const float* rowp = transfer + (size_t)(rowbase + r) * L + lane;
            #pragma unroll
            for (int k = 0; k < 16; ++k)
                E[k][r] = __expf(rowp[64 * k]);
        }

        if (tid < CPB) {                            // b_{2047} = 0, tag 0
            int j = rb * CPB + tid;
            STA(&bb0[j], pack_su(0, 0.f));
        }

        for (int s = 1; s <= BSTEPS; ++s) {
            uint64_t* rbuf = (s & 1) ? bb0 : bb1;
            uint64_t* wbuf = (s & 1) ? bb1 : bb0;
            const int expect = s - 1;
            const int t = T_LEN - s;                // emission row for this step

            // prefetch emission chunk for my 4 j's (overlaps poll)
            const float4 fv = *(const float4*)(feats + (size_t)t * L + 4 * tid);

            const uint64_t* rp = rbuf + 4 * tid;
            uint64_t v0, v1, v2, v3, vs;
            int n = 0;
            for (;;) {
                v0 = LDA(rp + 0); v1 = LDA(rp + 1);
                v2 = LDA(rp + 2); v3 = LDA(rp + 3);
                vs = LDA(rbuf + shslot);
                bool ready = ((int)(v0 >> 32) >= expect) & ((int)(v1 >> 32) >= expect) &
                             ((int)(v2 >> 32) >= expect) & ((int)(v3 >> 32) >= expect) &
                             ((int)(vs >> 32) >= expect);
                if (ready || ++n >= SPIN_MAX) break;
            }
            const float sb = __uint_as_float((uint32_t)vs);

            // w_j = exp(feats[t][j] + b[j] - sb) -> LDS broadcast
            float* qb = qbuf[s & 1];
            float4 wv4;
            wv4.x = __expf(fv.x + __uint_as_float((uint32_t)v0) - sb);
            wv4.y = __expf(fv.y + __uint_as_float((uint32_t)v1) - sb);
            wv4.z = __expf(fv.z + __uint_as_float((uint32_t)v2) - sb);
            wv4.w = __expf(fv.w + __uint_as_float((uint32_t)v3) - sb);
            ((float4*)qb)[tid] = wv4;
            __syncthreads();

            // matvec: acc[r] += w[lane+64k] * E[k][r]
            float a0 = 0.f, a1 = 0.f, a2 = 0.f, a3 = 0.f;
            #pragma unroll
            for (int k = 0; k < 16; ++k) {
                const float w = qb[lane + 64 * k];
                a0 += w * E[k][0]; a1 += w * E[k][1];
                a2 += w * E[k][2]; a3 += w * E[k][3];
            }

            {   // split-reduction: 4 accs -> 1 per lane (row = cl)
                const bool h1 = lane & 1;
                float s0 = h1 ? a0 : a2;  float r0 = __shfl_xor(s0, 1, 64);
                float s1 = h1 ? a1 : a3;  float r1 = __shfl_xor(s1, 1, 64);
                a0 = (h1 ? a2 : a0) + r0;
                a1 = (h1 ? a3 : a1) + r1;
                const bool h2 = lane & 2;
                float s2 = h2 ? a0 : a1;  float r2 = __shfl_xor(s2, 2, 64);
                a0 = (h2 ? a1 : a0) + r2;
            }
            float sum = a0;
            sum += __shfl_xor(sum, 4, 64);
            sum += __shfl_xor(sum, 8, 64);
            sum += __shfl_xor(sum, 16, 64);
            sum += __shfl_xor(sum, 32, 64);

            const float nb = sb + __logf(sum);      // emission already inside w
            if (lane < 4)
                STA(&wbuf[rowbase + cl], pack_su(s, nb));
        }
    }
}

// =====================================================================
// Fallback: the proven R4 single-forward-chain kernel (4.16 ms).
// Requires only (2*L + 1) * 8 = 16392 bytes of ws.
// =====================================================================
__global__ __launch_bounds__(TPB, 1)
void crf_single(const float* __restrict__ feats,
                const float* __restrict__ transfer,
                const int* __restrict__ target,
                float* __restrict__ out,
                uint64_t* __restrict__ ws64)
{
    __shared__ __align__(16) float qbuf[2][L];
    __shared__ float red[8];

    uint64_t* buf0 = ws64;
    uint64_t* buf1 = ws64 + L;
    uint64_t* goldslot = ws64 + 2 * L;

    const int b   = blockIdx.x;
    const int tid = threadIdx.x;
    const int lane = tid & 63;
    const int wv   = tid >> 6;
    const int cl   = 2 * (lane & 1) + ((lane >> 1) & 1);

    if (b == NFB) {   // gold block
        float s = 0.f;
        for (int t = tid; t < T_LEN; t += TPB)
            s += feats[t * L + target[t]];
        for (int t = tid; t < T_LEN - 1; t += TPB)
            s += transfer[target[t] * L + target[t + 1]];
        #pragma unroll
        for (int m = 32; m; m >>= 1) s += __shfl_xor(s, m, 64);
        if (lane == 0) red[wv] = s;
        __syncthreads();
        if (tid == 0) {
            float g = red[0] + red[1] + red[2] + red[3];
            STA(goldslot, pack_su(1, g));
        }
        return;
    }

    const int gcb    = b * CPB + 4 * wv;
    const int shslot = b * CPB;

    float E[16][4];
    #pragma unroll
    for (int k = 0; k < 16; ++k) {
        const float4 r = *(const float4*)(transfer + (size_t)(lane + 64 * k) * L + gcb);
        E[k][0] = __expf(r.x); E[k][1] = __expf(r.y);
        E[k][2] = __expf(r.z); E[k][3] = __expf(r.w);
    }

    if (tid < CPB) {
        int j = b * CPB + tid;
        STA(&buf0[j], pack_su(0, feats[j]));
    }

    for (int t = 1; t < T_LEN; ++t) {
        uint64_t* rbuf = (t & 1) ? buf0 : buf1;
        uint64_t* wbuf = (t & 1) ? buf1 : buf0;
        const int expect = t - 1;
        const float fe = feats[(size_t)t * L + gcb + cl];

        const uint64_t* rp = rbuf + 4 * tid;
        uint64_t v0, v1, v2, v3, vs;
        int n = 0;
        for (;;) {
            v0 = LDA(rp + 0); v1 = LDA(rp + 1);
            v2 = LDA(rp + 2); v3 = LDA(rp + 3);
            vs = LDA(rbuf + shslot);
            bool ready = ((int)(v0 >> 32) >= expect) & ((int)(v1 >> 32) >= expect) &
                         ((int)(v2 >> 32) >= expect) & ((int)(v3 >> 32) >= expect) &
                         ((int)(vs >> 32) >= expect);
            if (ready || ++n >= SPIN_MAX) break;
        }
        const float sloc = __uint_as_float((uint32_t)vs);

        float* qb = qbuf[t & 1];
        float4 qv;
        qv.x = __expf(__uint_as_float((uint32_t)v0) - sloc);
        qv.y = __expf(__uint_as_float((uint32_t)v1) - sloc);
        qv.z = __expf(__uint_as_float((uint32_t)v2) - sloc);
        qv.w = __expf(__uint_as_float((uint32_t)v3) - sloc);
        ((float4*)qb)[tid] = qv;
        __syncthreads();

        float a0 = 0.f, a1 = 0.f, a2 = 0.f, a3 = 0.f;
        #pragma unroll
        for (int k = 0; k < 16; ++k) {
            const float q = qb[lane + 64 * k];
            a0 += q * E[k][0]; a1 += q * E[k][1];
            a2 += q * E[k][2]; a3 += q * E[k][3];
        }
        {
            const bool h1 = lane & 1;
            float s0 = h1 ? a0 : a2;  float r0 = __shfl_xor(s0, 1, 64);
            float s1 = h1 ? a1 : a3;  float r1 = __shfl_xor(s1, 1, 64);
            a0 = (h1 ? a2 : a0) + r0;
            a1 = (h1 ? a3 : a1) + r1;
            const bool h2 = lane & 2;
            float s2 = h2 ? a0 : a1;  float r2 = __shfl_xor(s2, 2, 64);
            a0 = (h2 ? a1 : a0) + r2;
        }
        float s = a0;
        s += __shfl_xor(s, 4, 64);
        s += __shfl_xor(s, 8, 64);
        s += __shfl_xor(s, 16, 64);
        s += __shfl_xor(s, 32, 64);

        const float nv = sloc + __logf(s) + fe;
        if (lane < 4)
            STA(&wbuf[gcb + cl], pack_su(t, nv));
    }

    if (b == 0) {
        const uint64_t* fp = buf1 + 4 * tid;
        uint64_t v0, v1, v2, v3;
        int n = 0;
        for (;;) {
            v0 = LDA(fp + 0); v1 = LDA(fp + 1);
            v2 = LDA(fp + 2); v3 = LDA(fp + 3);
            bool ready = ((int)(v0 >> 32) >= T_LEN - 1) & ((int)(v1 >> 32) >= T_LEN - 1) &
                         ((int)(v2 >> 32) >= T_LEN - 1) & ((int)(v3 >> 32) >= T_LEN - 1);
            if (ready || ++n >= SPIN_MAX) break;
        }
        float sv[4] = { __uint_as_float((uint32_t)v0), __uint_as_float((uint32_t)v1),
                        __uint_as_float((uint32_t)v2), __uint_as_float((uint32_t)v3) };
        float mx = fmaxf(fmaxf(sv[0], sv[1]), fmaxf(sv[2], sv[3]));
        #pragma unroll
        for (int m = 32; m; m >>= 1) mx = fmaxf(mx, __shfl_xor(mx, m, 64));
        if (lane == 0) red[wv] = mx;
        __syncthreads();
        const float M = fmaxf(fmaxf(red[0], red[1]), fmaxf(red[2], red[3]));
        float sm = 0.f;
        #pragma unroll
        for (int k = 0; k < 4; ++k) sm += __expf(sv[k] - M);
        #pragma unroll
        for (int m = 32; m; m >>= 1) sm += __shfl_xor(sm, m, 64);
        if (lane == 0) red[4 + wv] = sm;
        __syncthreads();
        if (tid == 0) {
            const float S = red[4] + red[5] + red[6] + red[7];
            const float lse = M + __logf(S);
            uint64_t g = LDA(goldslot);
            int n2 = 0;
            while ((int)(g >> 32) < 1 && ++n2 < SPIN_MAX) g = LDA(goldslot);
            out[0] = lse - __uint_as_float((uint32_t)g);
        }
    }
}

extern "C" void kernel_launch(void* const* d_in, const int* in_sizes, int n_in,
                              void* d_out, int out_size, void* d_ws, size_t ws_size,
                              hipStream_t stream) {
    const float* feats    = (const float*)d_in[0];
    const float* transfer = (const float*)d_in[1];
    const int*   target   = (const int*)d_in[2];
    float* out = (float*)d_out;
    uint64_t* ws64 = (uint64_t*)d_ws;

    if (ws_size >= (4 * L + 1) * sizeof(uint64_t)) {
        // meet-in-the-middle: forward + backward chains, critical path 1024 steps
        hipLaunchKernelGGL(crf_mitm, dim3(GOLDB + 1), dim3(TPB), 0, stream,
                           feats, transfer, target, out, ws64);
    } else {
        // proven single-chain fallback (R4): needs only 16392 B of ws
        hipLaunchKernelGGL(crf_single, dim3(NFB + 1), dim3(TPB), 0, stream,
                           feats, transfer, target, out, ws64);
    }
}